// Round 7
// baseline (481.573 us; speedup 1.0000x reference)
//
#include <hip/hip_runtime.h>
#include <hip/hip_bf16.h>
#include <stdint.h>

#define B_  32
#define L_  256
#define T_  32
#define D_  300
#define H_  256
#define G3  768   // 3*H

typedef _Float16 half2_t __attribute__((ext_vector_type(2)));

__device__ __forceinline__ float fdot2(uint32_t w, uint32_t h, float acc) {
#if defined(__has_builtin) && __has_builtin(__builtin_amdgcn_fdot2)
  return __builtin_amdgcn_fdot2(__builtin_bit_cast(half2_t, w),
                                __builtin_bit_cast(half2_t, h), acc, false);
#else
  half2_t a = __builtin_bit_cast(half2_t, w);
  half2_t b = __builtin_bit_cast(half2_t, h);
  return acc + (float)a[0] * (float)b[0] + (float)a[1] * (float)b[1];
#endif
}

__device__ __forceinline__ uint32_t pack2(float x, float y) {
  half2_t h;
  h[0] = (_Float16)x;
  h[1] = (_Float16)y;
  return __builtin_bit_cast(uint32_t, h);
}

__device__ __forceinline__ float rcp_f(float x) { return __builtin_amdgcn_rcpf(x); }
__device__ __forceinline__ float sigmoid_f(float x) { return rcp_f(1.0f + __expf(-x)); }
__device__ __forceinline__ float tanh_f(float x) {
  float e2 = __expf(2.0f * x);
  return 1.0f - 2.0f * rcp_f(e2 + 1.0f);
}

// ---- pack Whh [768][256] f32 -> wT2 [128][768] f16x2 (pairs along K) ----
__global__ void pack_whh(const float* __restrict__ Whh, uint32_t* __restrict__ wT2) {
  const int idx = blockIdx.x * 256 + threadIdx.x;   // 0..98303
  const int row = idx % G3;
  const int kk  = idx / G3;
  wT2[idx] = pack2(Whh[row * H_ + 2 * kk], Whh[row * H_ + 2 * kk + 1]);
}

// ---- bsum = bih + bhh for gates r,z; bih only for gate n (bhh_n is inside r*(.)) ----
__global__ void bias_combine(const float* __restrict__ bih, const float* __restrict__ bhh,
                             float* __restrict__ bsum) {
  const int i = blockIdx.x * 256 + threadIdx.x;   // 0..767
  float v = bih[i];
  if (i < 2 * H_) v += bhh[i];
  bsum[i] = v;
}

// ---- dtok[i] = Xin[b*L + Xindex[i]] ----
__global__ void gather_dtok(const int* __restrict__ Xin, const int* __restrict__ Xindex,
                            int* __restrict__ dtok) {
  const int i = blockIdx.x * 256 + threadIdx.x;   // 0..1023
  const int b = i >> 5;                           // /T_
  dtok[i] = Xin[b * L_ + Xindex[i]];
}

// ---- generic C = A @ W^T (+bias), A rows optionally gathered; out optionally
//      stored transposed per 256-row batch: C[b][n][l], m = b*256+l ----
template<bool GATHER, bool TRANSP, bool BIAS>
__global__ __launch_bounds__(256)
void gemm_awt(const float* __restrict__ A, const int* __restrict__ rowidx,
              const float* __restrict__ W, const float* __restrict__ bias,
              float* __restrict__ C, int M, int N, int K) {
  __shared__ float As[16][68];
  __shared__ float Ws[16][68];
  const int tid = threadIdx.x;
  const int bm = blockIdx.x, bn = blockIdx.y;
  const int ty = tid >> 4, tx = tid & 15;
  const int r  = tid >> 2;
  const int c4 = (tid & 3) << 2;
  const long arow = (long)bm * 64 + r;
  const float* Arow = GATHER ? (A + (long)rowidx[arow] * K) : (A + arow * (long)K);
  const float* Wrow = W + ((long)bn * 64 + r) * K;
  float acc[4][4] = {};
  for (int k0 = 0; k0 < K; k0 += 16) {
    float4 av, wv;
    if (k0 + c4 + 3 < K) {
      av = *(const float4*)(Arow + k0 + c4);
      wv = *(const float4*)(Wrow + k0 + c4);
    } else {
      float ta[4] = {0, 0, 0, 0}, tw[4] = {0, 0, 0, 0};
      for (int u = 0; u < 4; ++u)
        if (k0 + c4 + u < K) { ta[u] = Arow[k0 + c4 + u]; tw[u] = Wrow[k0 + c4 + u]; }
      av.x = ta[0]; av.y = ta[1]; av.z = ta[2]; av.w = ta[3];
      wv.x = tw[0]; wv.y = tw[1]; wv.z = tw[2]; wv.w = tw[3];
    }
    __syncthreads();
    As[c4 + 0][r] = av.x; As[c4 + 1][r] = av.y; As[c4 + 2][r] = av.z; As[c4 + 3][r] = av.w;
    Ws[c4 + 0][r] = wv.x; Ws[c4 + 1][r] = wv.y; Ws[c4 + 2][r] = wv.z; Ws[c4 + 3][r] = wv.w;
    __syncthreads();
#pragma unroll
    for (int k = 0; k < 16; ++k) {
      const float4 a4 = *(const float4*)&As[k][ty << 2];
      const float4 b4 = *(const float4*)&Ws[k][tx << 2];
      acc[0][0] = fmaf(a4.x, b4.x, acc[0][0]);
      acc[0][1] = fmaf(a4.x, b4.y, acc[0][1]);
      acc[0][2] = fmaf(a4.x, b4.z, acc[0][2]);
      acc[0][3] = fmaf(a4.x, b4.w, acc[0][3]);
      acc[1][0] = fmaf(a4.y, b4.x, acc[1][0]);
      acc[1][1] = fmaf(a4.y, b4.y, acc[1][1]);
      acc[1][2] = fmaf(a4.y, b4.z, acc[1][2]);
      acc[1][3] = fmaf(a4.y, b4.w, acc[1][3]);
      acc[2][0] = fmaf(a4.z, b4.x, acc[2][0]);
      acc[2][1] = fmaf(a4.z, b4.y, acc[2][1]);
      acc[2][2] = fmaf(a4.z, b4.z, acc[2][2]);
      acc[2][3] = fmaf(a4.z, b4.w, acc[2][3]);
      acc[3][0] = fmaf(a4.w, b4.x, acc[3][0]);
      acc[3][1] = fmaf(a4.w, b4.y, acc[3][1]);
      acc[3][2] = fmaf(a4.w, b4.z, acc[3][2]);
      acc[3][3] = fmaf(a4.w, b4.w, acc[3][3]);
    }
  }
#pragma unroll
  for (int i = 0; i < 4; ++i) {
    const int m = bm * 64 + (ty << 2) + i;
#pragma unroll
    for (int j = 0; j < 4; ++j) {
      const int n = bn * 64 + (tx << 2) + j;
      float v = acc[i][j];
      if (BIAS) v += bias[n];
      if (TRANSP) C[(((long)(m >> 8) * N + n) << 8) + (m & 255)] = v;
      else        C[(long)m * N + n] = v;
    }
  }
}

// ============ sequential GRU, 1024 threads, K split 4-way ============
// tid = q*256 + j. Thread owns rows {j, H+j, 2H+j}, K-pairs [q*32, q*32+32)
// = 96 weight dwords. Register plan: 96 weights + ~25 misc = ~121 <= 128.
// The allocator must be given a MAXIMUM occupancy, not just launch_bounds'
// minimum (r6: budget floor 4 waves/EU but allocator targeted 8 -> 64 VGPR
// -> scratch spill -> 2600 cy/step on the L2 path). amdgpu_waves_per_eu(4,4)
// + amdgpu_num_vgpr(128) pin the budget to 128 at 1 block/CU.

__device__ __forceinline__ uint4 ld4w(const uint32_t* __restrict__ b, int off, int c) {
  uint4 v;
  v.x = b[(4 * c + 0) * G3 + off];
  v.y = b[(4 * c + 1) * G3 + off];
  v.z = b[(4 * c + 2) * G3 + off];
  v.w = b[(4 * c + 3) * G3 + off];
  return v;
}

#define WDECL8(p) uint4 p##0, p##1, p##2, p##3, p##4, p##5, p##6, p##7
#define WLOAD8(p, base, off) \
  p##0 = ld4w(base, off, 0); p##1 = ld4w(base, off, 1); \
  p##2 = ld4w(base, off, 2); p##3 = ld4w(base, off, 3); \
  p##4 = ld4w(base, off, 4); p##5 = ld4w(base, off, 5); \
  p##6 = ld4w(base, off, 6); p##7 = ld4w(base, off, 7)
#define PIN4(v) asm volatile("" : "+v"(v.x), "+v"(v.y), "+v"(v.z), "+v"(v.w))
#define WPIN8(p) \
  PIN4(p##0); PIN4(p##1); PIN4(p##2); PIN4(p##3); \
  PIN4(p##4); PIN4(p##5); PIN4(p##6); PIN4(p##7)

#define STEP_I(i) { \
  const uint4 hp = hp8[i]; \
  ar = fdot2(wr##i.x, hp.x, ar); az = fdot2(wz##i.x, hp.x, az); an = fdot2(wn##i.x, hp.x, an); \
  ar = fdot2(wr##i.y, hp.y, ar); az = fdot2(wz##i.y, hp.y, az); an = fdot2(wn##i.y, hp.y, an); \
  ar = fdot2(wr##i.z, hp.z, ar); az = fdot2(wz##i.z, hp.z, az); an = fdot2(wn##i.z, hp.z, an); \
  ar = fdot2(wr##i.w, hp.w, ar); az = fdot2(wz##i.w, hp.w, az); an = fdot2(wn##i.w, hp.w, an); }

__global__ __attribute__((amdgpu_flat_work_group_size(1024, 1024),
                          amdgpu_waves_per_eu(4, 4),
                          amdgpu_num_vgpr(128)))
void gru_seq(const float* __restrict__ xg, const uint32_t* __restrict__ wT2,
             const float* __restrict__ bhh, const float* __restrict__ h0,
             float* __restrict__ hout, float* __restrict__ hlast, int S) {
  const int b = blockIdx.x;
  const int tid = threadIdx.x;
  const int j = tid & 255;
  const int q = tid >> 8;
  const uint32_t* wbase = wT2 + (size_t)q * 32 * G3;  // kk base = q*32 pairs
  WDECL8(wr); WDECL8(wz); WDECL8(wn);
  WLOAD8(wr, wbase, j);
  WLOAD8(wz, wbase, H_ + j);
  WLOAD8(wn, wbase, 2 * H_ + j);
  WPIN8(wr); WPIN8(wz); WPIN8(wn);
  __shared__ __align__(16) uint32_t h2[H_ / 2];
  __shared__ float part[3][4][H_];   // [gate][q][j]; q=0 slice unused
  float bhn = 0.0f, h = 0.0f;
  const float* xp = xg + (long)b * S * G3;
  float* hp_out = hout + (long)b * S * H_;
  if (q == 0) {
    bhn = bhh[2 * H_ + j];
    h = h0 ? h0[b * H_ + j] : 0.0f;
    ((_Float16*)h2)[j] = (_Float16)h;
  }
  __syncthreads();
  for (int t = 0; t < S; ++t) {
    float xr = 0.0f, xz = 0.0f, xn = 0.0f;
    if (q == 0) { xr = xp[j]; xz = xp[H_ + j]; xn = xp[2 * H_ + j]; }
    float ar = 0.0f, az = 0.0f, an = 0.0f;
    const uint4* hp8 = (const uint4*)h2 + q * 8;
    STEP_I(0) STEP_I(1)
    __builtin_amdgcn_sched_barrier(0);   // cap hp liveness: <=2 uint4 per region
    STEP_I(2) STEP_I(3)
    __builtin_amdgcn_sched_barrier(0);
    STEP_I(4) STEP_I(5)
    __builtin_amdgcn_sched_barrier(0);
    STEP_I(6) STEP_I(7)
    if (q) { part[0][q][j] = ar; part[1][q][j] = az; part[2][q][j] = an; }
    __syncthreads();
    if (q == 0) {
      ar += part[0][1][j] + part[0][2][j] + part[0][3][j];
      az += part[1][1][j] + part[1][2][j] + part[1][3][j];
      an += part[2][1][j] + part[2][2][j] + part[2][3][j];
      const float r = sigmoid_f(xr + ar);        // xr includes bih_r + bhh_r
      const float z = sigmoid_f(xz + az);        // xz includes bih_z + bhh_z
      const float n = tanh_f(xn + r * (an + bhn));
      h = (1.0f - z) * n + z * h;
      hp_out[j] = h;
      ((_Float16*)h2)[j] = (_Float16)h;
    }
    xp += G3;
    hp_out += H_;
    __syncthreads();
  }
  if (q == 0 && hlast) hlast[b * H_ + j] = h;
}

// ---- fused pointer layer + masked log-softmax + loss accumulation ----
// grid (T, B), 256 threads = one per l. WEt is [b][h][l] (transposed).
__global__ __launch_bounds__(256)
void pointer_loss(const float* __restrict__ WEt, const float* __restrict__ WD,
                  const float* __restrict__ Vv,
                  const int* __restrict__ Xindex, const int* __restrict__ Yindex,
                  const int* __restrict__ lens, float* __restrict__ out) {
  const int t = blockIdx.x, b = blockIdx.y;
  const int l = threadIdx.x;
  __shared__ float wd_s[H_], vv_s[H_];
  __shared__ float rbuf[4], sbuf[4], vy_s;
  const int bt = b * T_ + t;
  wd_s[l] = WD[(long)bt * H_ + l];
  vv_s[l] = Vv[l] * 1.0507009873554805f;   // fold selu scale of inner selu into Vv
  __syncthreads();
  const float* wet = WEt + (long)b * H_ * L_;
  const float alpha = 1.6732632423543772f;
  float acc = 0.0f;
#pragma unroll 4
  for (int hh = 0; hh < H_; ++hh) {
    const float xsum = wet[hh * L_ + l] + wd_s[hh];
    const float sneg = alpha * (__expf(xsum) - 1.0f);
    const float s = xsum > 0.0f ? xsum : sneg;
    acc = fmaf(s, vv_s[hh], acc);
  }
  float v;
  {
    const float sneg = alpha * (__expf(acc) - 1.0f);
    v = 1.0507009873554805f * (acc > 0.0f ? acc : sneg);
  }
  const int start = Xindex[bt];
  const int len = lens[b];
  const bool valid = (l >= start) && (l < len);
  const int y = Yindex[bt];
  if (l == y) vy_s = v;
  float m = valid ? v : -INFINITY;
  for (int off = 32; off > 0; off >>= 1) m = fmaxf(m, __shfl_xor(m, off, 64));
  const int wid = l >> 6, lane = l & 63;
  if (lane == 0) rbuf[wid] = m;
  __syncthreads();
  const float mx = fmaxf(fmaxf(rbuf[0], rbuf[1]), fmaxf(rbuf[2], rbuf[3]));
  float e = valid ? __expf(v - mx) : 0.0f;
  for (int off = 32; off > 0; off >>= 1) e += __shfl_xor(e, off, 64);
  if (lane == 0) sbuf[wid] = e;
  __syncthreads();
  if (l == 0) {
    const float sum = sbuf[0] + sbuf[1] + sbuf[2] + sbuf[3];
    atomicAdd(out, (mx + __logf(sum) - vy_s) * (1.0f / (B_ * T_)));
  }
}

extern "C" void kernel_launch(void* const* d_in, const int* in_sizes, int n_in,
                              void* d_out, int out_size, void* d_ws, size_t ws_size,
                              hipStream_t stream) {
  (void)in_sizes; (void)n_in; (void)out_size; (void)ws_size;
  const int*   Xin    = (const int*)d_in[0];
  const int*   Xindex = (const int*)d_in[1];
  const int*   Yindex = (const int*)d_in[2];
  const int*   lens   = (const int*)d_in[3];
  const float* emb    = (const float*)d_in[4];
  const float* Wih_e  = (const float*)d_in[5];
  const float* Whh_e  = (const float*)d_in[6];
  const float* bih_e  = (const float*)d_in[7];
  const float* bhh_e  = (const float*)d_in[8];
  const float* Wih_d  = (const float*)d_in[9];
  const float* Whh_d  = (const float*)d_in[10];
  const float* bih_d  = (const float*)d_in[11];
  const float* bhh_d  = (const float*)d_in[12];
  const float* W1     = (const float*)d_in[13];
  const float* W2     = (const float*)d_in[14];
  const float* Vv     = (const float*)d_in[15];

  char* p = (char*)d_ws;
  auto take = [&](size_t bytes) { void* q = (void*)p; p += (bytes + 255) & ~(size_t)255; return q; };
  uint32_t* wT2_e = (uint32_t*)take((size_t)98304 * 4);
  uint32_t* wT2_d = (uint32_t*)take((size_t)98304 * 4);
  float* xg_e  = (float*)take((size_t)8192 * 768 * 4);
  float* xg_d  = (float*)take((size_t)1024 * 768 * 4);
  float* hn    = (float*)take((size_t)8192 * 256 * 4);
  float* hend  = (float*)take((size_t)8192 * 4);
  float* hl_d  = (float*)take((size_t)8192 * 4);
  float* doutb = (float*)take((size_t)1024 * 256 * 4);
  float* WEt   = (float*)take((size_t)8192 * 256 * 4);
  float* WDb   = (float*)take((size_t)1024 * 256 * 4);
  int*   dtok  = (int*)take((size_t)1024 * 4);
  float* bsum_e = (float*)take((size_t)768 * 4);
  float* bsum_d = (float*)take((size_t)768 * 4);

  hipMemsetAsync(d_out, 0, sizeof(float), stream);

  hipLaunchKernelGGL(pack_whh, dim3(384), dim3(256), 0, stream, Whh_e, wT2_e);
  hipLaunchKernelGGL(pack_whh, dim3(384), dim3(256), 0, stream, Whh_d, wT2_d);
  hipLaunchKernelGGL(bias_combine, dim3(3), dim3(256), 0, stream, bih_e, bhh_e, bsum_e);
  hipLaunchKernelGGL(bias_combine, dim3(3), dim3(256), 0, stream, bih_d, bhh_d, bsum_d);
  hipLaunchKernelGGL(gather_dtok, dim3(4), dim3(256), 0, stream, Xin, Xindex, dtok);

  // xg_e = emb[Xin] @ Wih_e^T + (bih_e + bhh_e|rz)   [8192 x 768], K=300
  hipLaunchKernelGGL((gemm_awt<true, false, true>), dim3(128, 12), dim3(256), 0, stream,
                     emb, Xin, Wih_e, bsum_e, xg_e, 8192, 768, 300);
  // xg_d = emb[dtok] @ Wih_d^T + (bih_d + bhh_d|rz)  [1024 x 768], K=300
  hipLaunchKernelGGL((gemm_awt<true, false, true>), dim3(16, 12), dim3(256), 0, stream,
                     emb, dtok, Wih_d, bsum_d, xg_d, 1024, 768, 300);

  // encoder GRU (h0 = 0), outputs hn [B,L,H] and hend [B,H]
  hipLaunchKernelGGL(gru_seq, dim3(32), dim3(1024), 0, stream,
                     xg_e, wT2_e, bhh_e, (const float*)nullptr, hn, hend, L_);
  // decoder GRU (h0 = hend), outputs doutb [B,T,H]
  hipLaunchKernelGGL(gru_seq, dim3(32), dim3(1024), 0, stream,
                     xg_d, wT2_d, bhh_d, hend, doutb, hl_d, T_);

  // WEt[b][k][l] = sum_h hn[b,l,h] * W1[k,h]   (transposed store)
  hipLaunchKernelGGL((gemm_awt<false, true, false>), dim3(128, 4), dim3(256), 0, stream,
                     hn, (const int*)nullptr, W1, (const float*)nullptr, WEt, 8192, 256, 256);
  // WD[b,t,k] = sum_h doutb[b,t,h] * W2[k,h]
  hipLaunchKernelGGL((gemm_awt<false, false, false>), dim3(16, 4), dim3(256), 0, stream,
                     doutb, (const int*)nullptr, W2, (const float*)nullptr, WDb, 1024, 256, 256);

  // fused pointer layer + loss
  hipLaunchKernelGGL(pointer_loss, dim3(T_, B_), dim3(256), 0, stream,
                     WEt, WDb, Vv, Xindex, Yindex, lens, (float*)d_out);
}

// Round 8
// 365.298 us; speedup vs baseline: 1.3183x; 1.3183x over previous
//
#include <hip/hip_runtime.h>
#include <hip/hip_bf16.h>
#include <stdint.h>

#define B_  32
#define L_  256
#define T_  32
#define D_  300
#define H_  256
#define G3  768   // 3*H

__device__ __forceinline__ int sdot4(uint32_t a, uint32_t b, int acc) {
#if defined(__has_builtin) && __has_builtin(__builtin_amdgcn_sdot4)
  return __builtin_amdgcn_sdot4((int)a, (int)b, acc, false);
#else
  const int a0 = (int)(signed char)(a & 0xff),  b0 = (int)(signed char)(b & 0xff);
  const int a1 = (int)(signed char)((a >> 8) & 0xff),  b1 = (int)(signed char)((b >> 8) & 0xff);
  const int a2 = (int)(signed char)((a >> 16) & 0xff), b2 = (int)(signed char)((b >> 16) & 0xff);
  const int a3 = (int)(signed char)(a >> 24),          b3 = (int)(signed char)(b >> 24);
  return acc + a0 * b0 + a1 * b1 + a2 * b2 + a3 * b3;
#endif
}

__device__ __forceinline__ float rcp_f(float x) { return __builtin_amdgcn_rcpf(x); }
__device__ __forceinline__ float sigmoid_f(float x) { return rcp_f(1.0f + __expf(-x)); }
__device__ __forceinline__ float tanh_f(float x) {
  float e2 = __expf(2.0f * x);
  return 1.0f - 2.0f * rcp_f(e2 + 1.0f);
}

// ---- pack Whh [768][256] f32 -> wQ i8 [64 kgroups][768 rows] + sw[768] ----
// one wave per row. sw is pre-multiplied by 1/127 (h scale), so a = dot * sw.
__global__ __launch_bounds__(256)
void pack_whh_i8(const float* __restrict__ Whh, uint32_t* __restrict__ wQ,
                 float* __restrict__ sw) {
  const int row = blockIdx.x * 4 + (threadIdx.x >> 6);
  const int lane = threadIdx.x & 63;
  const float* wr = Whh + (long)row * H_;
  float m = 0.0f;
#pragma unroll
  for (int u = 0; u < 4; ++u) m = fmaxf(m, fabsf(wr[lane + 64 * u]));
  for (int off = 32; off > 0; off >>= 1) m = fmaxf(m, __shfl_xor(m, off, 64));
  const float inv = m > 0.0f ? 127.0f / m : 0.0f;
  if (lane == 0) sw[row] = m > 0.0f ? m / (127.0f * 127.0f) : 0.0f;
  // lane c packs k-group c (k = 4c..4c+3)
  uint32_t d = 0;
#pragma unroll
  for (int u = 0; u < 4; ++u) {
    int qv = __float2int_rn(wr[4 * lane + u] * inv);
    qv = qv > 127 ? 127 : (qv < -127 ? -127 : qv);
    d |= ((uint32_t)(qv & 0xff)) << (8 * u);
  }
  wQ[lane * G3 + row] = d;
}

// ---- bsum = bih + bhh for gates r,z; bih only for gate n (bhh_n is inside r*(.)) ----
__global__ void bias_combine(const float* __restrict__ bih, const float* __restrict__ bhh,
                             float* __restrict__ bsum) {
  const int i = blockIdx.x * 256 + threadIdx.x;   // 0..767
  float v = bih[i];
  if (i < 2 * H_) v += bhh[i];
  bsum[i] = v;
}

// ---- dtok[i] = Xin[b*L + Xindex[i]] ----
__global__ void gather_dtok(const int* __restrict__ Xin, const int* __restrict__ Xindex,
                            int* __restrict__ dtok) {
  const int i = blockIdx.x * 256 + threadIdx.x;   // 0..1023
  const int b = i >> 5;                           // /T_
  dtok[i] = Xin[b * L_ + Xindex[i]];
}

// ---- generic C = A @ W^T (+bias), A rows optionally gathered; out optionally
//      stored transposed per 256-row batch: C[b][n][l], m = b*256+l ----
template<bool GATHER, bool TRANSP, bool BIAS>
__global__ __launch_bounds__(256)
void gemm_awt(const float* __restrict__ A, const int* __restrict__ rowidx,
              const float* __restrict__ W, const float* __restrict__ bias,
              float* __restrict__ C, int M, int N, int K) {
  __shared__ float As[16][68];
  __shared__ float Ws[16][68];
  const int tid = threadIdx.x;
  const int bm = blockIdx.x, bn = blockIdx.y;
  const int ty = tid >> 4, tx = tid & 15;
  const int r  = tid >> 2;
  const int c4 = (tid & 3) << 2;
  const long arow = (long)bm * 64 + r;
  const float* Arow = GATHER ? (A + (long)rowidx[arow] * K) : (A + arow * (long)K);
  const float* Wrow = W + ((long)bn * 64 + r) * K;
  float acc[4][4] = {};
  for (int k0 = 0; k0 < K; k0 += 16) {
    float4 av, wv;
    if (k0 + c4 + 3 < K) {
      av = *(const float4*)(Arow + k0 + c4);
      wv = *(const float4*)(Wrow + k0 + c4);
    } else {
      float ta[4] = {0, 0, 0, 0}, tw[4] = {0, 0, 0, 0};
      for (int u = 0; u < 4; ++u)
        if (k0 + c4 + u < K) { ta[u] = Arow[k0 + c4 + u]; tw[u] = Wrow[k0 + c4 + u]; }
      av.x = ta[0]; av.y = ta[1]; av.z = ta[2]; av.w = ta[3];
      wv.x = tw[0]; wv.y = tw[1]; wv.z = tw[2]; wv.w = tw[3];
    }
    __syncthreads();
    As[c4 + 0][r] = av.x; As[c4 + 1][r] = av.y; As[c4 + 2][r] = av.z; As[c4 + 3][r] = av.w;
    Ws[c4 + 0][r] = wv.x; Ws[c4 + 1][r] = wv.y; Ws[c4 + 2][r] = wv.z; Ws[c4 + 3][r] = wv.w;
    __syncthreads();
#pragma unroll
    for (int k = 0; k < 16; ++k) {
      const float4 a4 = *(const float4*)&As[k][ty << 2];
      const float4 b4 = *(const float4*)&Ws[k][tx << 2];
      acc[0][0] = fmaf(a4.x, b4.x, acc[0][0]);
      acc[0][1] = fmaf(a4.x, b4.y, acc[0][1]);
      acc[0][2] = fmaf(a4.x, b4.z, acc[0][2]);
      acc[0][3] = fmaf(a4.x, b4.w, acc[0][3]);
      acc[1][0] = fmaf(a4.y, b4.x, acc[1][0]);
      acc[1][1] = fmaf(a4.y, b4.y, acc[1][1]);
      acc[1][2] = fmaf(a4.y, b4.z, acc[1][2]);
      acc[1][3] = fmaf(a4.y, b4.w, acc[1][3]);
      acc[2][0] = fmaf(a4.z, b4.x, acc[2][0]);
      acc[2][1] = fmaf(a4.z, b4.y, acc[2][1]);
      acc[2][2] = fmaf(a4.z, b4.z, acc[2][2]);
      acc[2][3] = fmaf(a4.z, b4.w, acc[2][3]);
      acc[3][0] = fmaf(a4.w, b4.x, acc[3][0]);
      acc[3][1] = fmaf(a4.w, b4.y, acc[3][1]);
      acc[3][2] = fmaf(a4.w, b4.z, acc[3][2]);
      acc[3][3] = fmaf(a4.w, b4.w, acc[3][3]);
    }
  }
#pragma unroll
  for (int i = 0; i < 4; ++i) {
    const int m = bm * 64 + (ty << 2) + i;
#pragma unroll
    for (int j = 0; j < 4; ++j) {
      const int n = bn * 64 + (tx << 2) + j;
      float v = acc[i][j];
      if (BIAS) v += bias[n];
      if (TRANSP) C[(((long)(m >> 8) * N + n) << 8) + (m & 255)] = v;
      else        C[(long)m * N + n] = v;
    }
  }
}

// ============ sequential GRU, 1024 threads, K split 4-way, i8 dot4 ==========
// tid = q*256 + j. Thread owns rows {j, H+j, 2H+j}, k-groups [q*16, q*16+16)
// = 48 weight dwords (i8x4). Streaming floor halves vs f16 (196 KB/step vs
// 393 at the ~150 B/cy per-CU L2 port that bounds rounds 2-7), and dot4 is
// 1 inst / 4 MACs. i32 accumulation exact; h quantized to i8 (|h|<1) only
// for the matvec - the z*h recurrence keeps f32 h.

__device__ __forceinline__ uint4 ld4q(const uint32_t* __restrict__ b, int row, int u) {
  uint4 v;
  v.x = b[(4 * u + 0) * G3 + row];
  v.y = b[(4 * u + 1) * G3 + row];
  v.z = b[(4 * u + 2) * G3 + row];
  v.w = b[(4 * u + 3) * G3 + row];
  return v;
}

#define PIN4(v) asm volatile("" : "+v"(v.x), "+v"(v.y), "+v"(v.z), "+v"(v.w))
#define DOTS_U(u) { \
  ar = sdot4(wr##u.x, hp##u.x, ar); az = sdot4(wz##u.x, hp##u.x, az); an = sdot4(wn##u.x, hp##u.x, an); \
  ar = sdot4(wr##u.y, hp##u.y, ar); az = sdot4(wz##u.y, hp##u.y, az); an = sdot4(wn##u.y, hp##u.y, an); \
  ar = sdot4(wr##u.z, hp##u.z, ar); az = sdot4(wz##u.z, hp##u.z, az); an = sdot4(wn##u.z, hp##u.z, an); \
  ar = sdot4(wr##u.w, hp##u.w, ar); az = sdot4(wz##u.w, hp##u.w, az); an = sdot4(wn##u.w, hp##u.w, an); }

__global__ __attribute__((amdgpu_flat_work_group_size(1024, 1024), amdgpu_waves_per_eu(4, 4)))
void gru_seq(const float* __restrict__ xg, const uint32_t* __restrict__ wQ,
             const float* __restrict__ sw, const float* __restrict__ bhh,
             const float* __restrict__ h0, float* __restrict__ hout,
             float* __restrict__ hlast, int S) {
  const int b = blockIdx.x;
  const int tid = threadIdx.x;
  const int j = tid & 255;
  const int q = tid >> 8;
  const uint32_t* wbase = wQ + (size_t)q * 16 * G3;   // k-group base = q*16
  uint4 wr0 = ld4q(wbase, j, 0),          wr1 = ld4q(wbase, j, 1),
        wr2 = ld4q(wbase, j, 2),          wr3 = ld4q(wbase, j, 3);
  uint4 wz0 = ld4q(wbase, H_ + j, 0),     wz1 = ld4q(wbase, H_ + j, 1),
        wz2 = ld4q(wbase, H_ + j, 2),     wz3 = ld4q(wbase, H_ + j, 3);
  uint4 wn0 = ld4q(wbase, 2 * H_ + j, 0), wn1 = ld4q(wbase, 2 * H_ + j, 1),
        wn2 = ld4q(wbase, 2 * H_ + j, 2), wn3 = ld4q(wbase, 2 * H_ + j, 3);
  PIN4(wr0); PIN4(wr1); PIN4(wr2); PIN4(wr3);
  PIN4(wz0); PIN4(wz1); PIN4(wz2); PIN4(wz3);
  PIN4(wn0); PIN4(wn1); PIN4(wn2); PIN4(wn3);
  __shared__ __align__(16) uint32_t h2[H_ / 4];      // h as i8[256]
  __shared__ int part[3][4][H_];                     // [gate][q][j]; q=0 unused
  float bhn = 0.0f, h = 0.0f, swr = 0.0f, swz = 0.0f, swn = 0.0f;
  const float* xp = xg + (long)b * S * G3;
  float* hp_out = hout + (long)b * S * H_;
  if (q == 0) {
    bhn = bhh[2 * H_ + j];
    swr = sw[j]; swz = sw[H_ + j]; swn = sw[2 * H_ + j];
    h = h0 ? h0[b * H_ + j] : 0.0f;
    ((signed char*)h2)[j] = (signed char)__float2int_rn(h * 127.0f);
  }
  __syncthreads();
  for (int t = 0; t < S; ++t) {
    float xr = 0.0f, xz = 0.0f, xn = 0.0f;
    if (q == 0) { xr = xp[j]; xz = xp[H_ + j]; xn = xp[2 * H_ + j]; }
    int ar = 0, az = 0, an = 0;
    const uint4* hq = (const uint4*)h2 + q * 4;      // 16 dwords per quarter
    const uint4 hp0 = hq[0];
    const uint4 hp1 = hq[1];
    DOTS_U(0)
    __builtin_amdgcn_sched_barrier(0);
    const uint4 hp2 = hq[2];
    DOTS_U(1)
    __builtin_amdgcn_sched_barrier(0);
    const uint4 hp3 = hq[3];
    DOTS_U(2)
    __builtin_amdgcn_sched_barrier(0);
    DOTS_U(3)
    if (q) { part[0][q][j] = ar; part[1][q][j] = az; part[2][q][j] = an; }
    __syncthreads();
    if (q == 0) {
      const float arf = (float)(ar + part[0][1][j] + part[0][2][j] + part[0][3][j]) * swr;
      const float azf = (float)(az + part[1][1][j] + part[1][2][j] + part[1][3][j]) * swz;
      const float anf = (float)(an + part[2][1][j] + part[2][2][j] + part[2][3][j]) * swn;
      const float r = sigmoid_f(xr + arf);           // xr includes bih_r + bhh_r
      const float z = sigmoid_f(xz + azf);           // xz includes bih_z + bhh_z
      const float n = tanh_f(xn + r * (anf + bhn));
      h = (1.0f - z) * n + z * h;
      hp_out[j] = h;
      ((signed char*)h2)[j] = (signed char)__float2int_rn(h * 127.0f);
    }
    xp += G3;
    hp_out += H_;
    __syncthreads();
  }
  if (q == 0 && hlast) hlast[b * H_ + j] = h;
}

// ---- fused pointer layer + masked log-softmax + loss accumulation ----
// grid (T, B), 256 threads = one per l. WEt is [b][h][l] (transposed).
__global__ __launch_bounds__(256)
void pointer_loss(const float* __restrict__ WEt, const float* __restrict__ WD,
                  const float* __restrict__ Vv,
                  const int* __restrict__ Xindex, const int* __restrict__ Yindex,
                  const int* __restrict__ lens, float* __restrict__ out) {
  const int t = blockIdx.x, b = blockIdx.y;
  const int l = threadIdx.x;
  __shared__ float wd_s[H_], vv_s[H_];
  __shared__ float rbuf[4], sbuf[4], vy_s;
  const int bt = b * T_ + t;
  wd_s[l] = WD[(long)bt * H_ + l];
  vv_s[l] = Vv[l] * 1.0507009873554805f;   // fold selu scale of inner selu into Vv
  __syncthreads();
  const float* wet = WEt + (long)b * H_ * L_;
  const float alpha = 1.6732632423543772f;
  float acc = 0.0f;
#pragma unroll 4
  for (int hh = 0; hh < H_; ++hh) {
    const float xsum = wet[hh * L_ + l] + wd_s[hh];
    const float sneg = alpha * (__expf(xsum) - 1.0f);
    const float s = xsum > 0.0f ? xsum : sneg;
    acc = fmaf(s, vv_s[hh], acc);
  }
  float v;
  {
    const float sneg = alpha * (__expf(acc) - 1.0f);
    v = 1.0507009873554805f * (acc > 0.0f ? acc : sneg);
  }
  const int start = Xindex[bt];
  const int len = lens[b];
  const bool valid = (l >= start) && (l < len);
  const int y = Yindex[bt];
  if (l == y) vy_s = v;
  float m = valid ? v : -INFINITY;
  for (int off = 32; off > 0; off >>= 1) m = fmaxf(m, __shfl_xor(m, off, 64));
  const int wid = l >> 6, lane = l & 63;
  if (lane == 0) rbuf[wid] = m;
  __syncthreads();
  const float mx = fmaxf(fmaxf(rbuf[0], rbuf[1]), fmaxf(rbuf[2], rbuf[3]));
  float e = valid ? __expf(v - mx) : 0.0f;
  for (int off = 32; off > 0; off >>= 1) e += __shfl_xor(e, off, 64);
  if (lane == 0) sbuf[wid] = e;
  __syncthreads();
  if (l == 0) {
    const float sum = sbuf[0] + sbuf[1] + sbuf[2] + sbuf[3];
    atomicAdd(out, (mx + __logf(sum) - vy_s) * (1.0f / (B_ * T_)));
  }
}

extern "C" void kernel_launch(void* const* d_in, const int* in_sizes, int n_in,
                              void* d_out, int out_size, void* d_ws, size_t ws_size,
                              hipStream_t stream) {
  (void)in_sizes; (void)n_in; (void)out_size; (void)ws_size;
  const int*   Xin    = (const int*)d_in[0];
  const int*   Xindex = (const int*)d_in[1];
  const int*   Yindex = (const int*)d_in[2];
  const int*   lens   = (const int*)d_in[3];
  const float* emb    = (const float*)d_in[4];
  const float* Wih_e  = (const float*)d_in[5];
  const float* Whh_e  = (const float*)d_in[6];
  const float* bih_e  = (const float*)d_in[7];
  const float* bhh_e  = (const float*)d_in[8];
  const float* Wih_d  = (const float*)d_in[9];
  const float* Whh_d  = (const float*)d_in[10];
  const float* bih_d  = (const float*)d_in[11];
  const float* bhh_d  = (const float*)d_in[12];
  const float* W1     = (const float*)d_in[13];
  const float* W2     = (const float*)d_in[14];
  const float* Vv     = (const float*)d_in[15];

  char* p = (char*)d_ws;
  auto take = [&](size_t bytes) { void* q = (void*)p; p += (bytes + 255) & ~(size_t)255; return q; };
  uint32_t* wQ_e = (uint32_t*)take((size_t)64 * G3 * 4);
  uint32_t* wQ_d = (uint32_t*)take((size_t)64 * G3 * 4);
  float* sw_e  = (float*)take((size_t)768 * 4);
  float* sw_d  = (float*)take((size_t)768 * 4);
  float* xg_e  = (float*)take((size_t)8192 * 768 * 4);
  float* xg_d  = (float*)take((size_t)1024 * 768 * 4);
  float* hn    = (float*)take((size_t)8192 * 256 * 4);
  float* hend  = (float*)take((size_t)8192 * 4);
  float* hl_d  = (float*)take((size_t)8192 * 4);
  float* doutb = (float*)take((size_t)1024 * 256 * 4);
  float* WEt   = (float*)take((size_t)8192 * 256 * 4);
  float* WDb   = (float*)take((size_t)1024 * 256 * 4);
  int*   dtok  = (int*)take((size_t)1024 * 4);
  float* bsum_e = (float*)take((size_t)768 * 4);
  float* bsum_d = (float*)take((size_t)768 * 4);

  hipMemsetAsync(d_out, 0, sizeof(float), stream);

  hipLaunchKernelGGL(pack_whh_i8, dim3(192), dim3(256), 0, stream, Whh_e, wQ_e, sw_e);
  hipLaunchKernelGGL(pack_whh_i8, dim3(192), dim3(256), 0, stream, Whh_d, wQ_d, sw_d);
  hipLaunchKernelGGL(bias_combine, dim3(3), dim3(256), 0, stream, bih_e, bhh_e, bsum_e);
  hipLaunchKernelGGL(bias_combine, dim3(3), dim3(256), 0, stream, bih_d, bhh_d, bsum_d);
  hipLaunchKernelGGL(gather_dtok, dim3(4), dim3(256), 0, stream, Xin, Xindex, dtok);

  // xg_e = emb[Xin] @ Wih_e^T + (bih_e + bhh_e|rz)   [8192 x 768], K=300
  hipLaunchKernelGGL((gemm_awt<true, false, true>), dim3(128, 12), dim3(256), 0, stream,
                     emb, Xin, Wih_e, bsum_e, xg_e, 8192, 768, 300);
  // xg_d = emb[dtok] @ Wih_d^T + (bih_d + bhh_d|rz)  [1024 x 768], K=300
  hipLaunchKernelGGL((gemm_awt<true, false, true>), dim3(16, 12), dim3(256), 0, stream,
                     emb, dtok, Wih_d, bsum_d, xg_d, 1024, 768, 300);

  // encoder GRU (h0 = 0), outputs hn [B,L,H] and hend [B,H]
  hipLaunchKernelGGL(gru_seq, dim3(32), dim3(1024), 0, stream,
                     xg_e, wQ_e, sw_e, bhh_e, (const float*)nullptr, hn, hend, L_);
  // decoder GRU (h0 = hend), outputs doutb [B,T,H]
  hipLaunchKernelGGL(gru_seq, dim3(32), dim3(1024), 0, stream,
                     xg_d, wQ_d, sw_d, bhh_d, hend, doutb, hl_d, T_);

  // WEt[b][k][l] = sum_h hn[b,l,h] * W1[k,h]   (transposed store)
  hipLaunchKernelGGL((gemm_awt<false, true, false>), dim3(128, 4), dim3(256), 0, stream,
                     hn, (const int*)nullptr, W1, (const float*)nullptr, WEt, 8192, 256, 256);
  // WD[b,t,k] = sum_h doutb[b,t,h] * W2[k,h]
  hipLaunchKernelGGL((gemm_awt<false, false, false>), dim3(16, 4), dim3(256), 0, stream,
                     doutb, (const int*)nullptr, W2, (const float*)nullptr, WDb, 1024, 256, 256);

  // fused pointer layer + loss
  hipLaunchKernelGGL(pointer_loss, dim3(T_, B_), dim3(256), 0, stream,
                     WEt, WDb, Vv, Xindex, Yindex, lens, (float*)d_out);
}